// Round 6
// baseline (497.217 us; speedup 1.0000x reference)
//
#include <hip/hip_runtime.h>
#include <hip/hip_bf16.h>

#define D_NODE 64
#define D_EDGE 32
#define D_OUT  64
#define EPSF   1e-7f
#define CAP    64   // max edges/node kept (deg ~ Poisson(10): P(>64) ~ 1e-32)

typedef float f32x2 __attribute__((ext_vector_type(2)));

// ---------------------------------------------------------------------------
// Pass 1: bucket edges by destination, storing payload {edge_id, src[edge]}.
// ---------------------------------------------------------------------------
__global__ __launch_bounds__(256) void genconv_build_kernel(
    const int* __restrict__ src,
    const int* __restrict__ dst,
    int* __restrict__ cnt,            // [N] zero-init
    int2* __restrict__ slots,         // [N*CAP]
    int E)
{
    const int e = blockIdx.x * blockDim.x + threadIdx.x;
    if (e >= E) return;
    const int d = dst[e];
    const int pos = atomicAdd(&cnt[d], 1);
    if (pos < CAP)
        slots[(size_t)d * CAP + pos] = make_int2(e, src[e]);
}

// ---------------------------------------------------------------------------
// Pass 2: one wave per node, lane = output channel.
// R4 structure (uniform-address slot-pair loads -> s_load, readfirstlane
// scalarization) + two changes:
//  * inner product as float2 ext-vector math -> v_pk_fma_f32 (16 instead of
//    32 VALU ops per edge)
//  * 4 edges in flight per iteration (index-clamp + multiplicative mask for
//    the remainder) for 2x the memory-level parallelism.
// ---------------------------------------------------------------------------
__global__ __launch_bounds__(256) void genconv_gather_kernel(
    const float* __restrict__ node,   // [N, 64]
    const float* __restrict__ ef,     // [E, 32]
    const int* __restrict__ cnt,      // [N]
    const int2* __restrict__ slots,   // [N*CAP]
    const float* __restrict__ We,     // [32, 64]
    const float* __restrict__ be,     // [64]
    const float* __restrict__ Wm,     // [64, 64]
    const float* __restrict__ bm,     // [64]
    float* __restrict__ out,          // [N, 64]
    int N)
{
    __shared__ float wm_s[D_NODE * D_OUT];          // 16 KiB
    __shared__ __align__(16) float fbuf[4][D_NODE]; // per-wave broadcast buffer
    for (int i = threadIdx.x; i < D_NODE * D_OUT; i += blockDim.x)
        wm_s[i] = Wm[i];
    __syncthreads();

    const int lane  = threadIdx.x & 63;
    const int wslot = threadIdx.x >> 6;

    // Per-lane We column, packed in pairs along k for v_pk_fma_f32.
    f32x2 w2[D_EDGE / 2];
#pragma unroll
    for (int k = 0; k < D_EDGE / 2; ++k) {
        w2[k].x = We[(2 * k + 0) * D_OUT + lane];
        w2[k].y = We[(2 * k + 1) * D_OUT + lane];
    }
    const float bias_e = be[lane];
    const float bias_m = bm[lane];

    const int wid = (int)((blockIdx.x * blockDim.x + threadIdx.x) >> 6);
    const int nw  = (int)((gridDim.x * blockDim.x) >> 6);

    for (int n = wid; n < N; n += nw) {
        const size_t base = (size_t)n * D_NODE;
        const int c = min(cnt[n], CAP);
        const int2* sl = slots + (size_t)n * CAP;

        const float fres = node[base + lane];   // residual (independent)
        float num = 0.0f, den = 0.0f;

        for (int j = 0; j < c; j += 4) {
            const int last = c - 1;
            const int j1 = min(j + 1, last);
            const int j2 = min(j + 2, last);
            const int j3 = min(j + 3, last);
            const float k1 = (j + 1 < c) ? 1.0f : 0.0f;
            const float k2 = (j + 2 < c) ? 1.0f : 0.0f;
            const float k3 = (j + 3 < c) ? 1.0f : 0.0f;

            const int2 p0 = sl[j];
            const int2 p1 = sl[j1];
            const int2 p2 = sl[j2];
            const int2 p3 = sl[j3];
            const int e0 = __builtin_amdgcn_readfirstlane(p0.x);
            const int s0 = __builtin_amdgcn_readfirstlane(p0.y);
            const int e1 = __builtin_amdgcn_readfirstlane(p1.x);
            const int s1 = __builtin_amdgcn_readfirstlane(p1.y);
            const int e2 = __builtin_amdgcn_readfirstlane(p2.x);
            const int s2 = __builtin_amdgcn_readfirstlane(p2.y);
            const int e3 = __builtin_amdgcn_readfirstlane(p3.x);
            const int s3 = __builtin_amdgcn_readfirstlane(p3.y);

            const f32x2* ep0 = (const f32x2*)(ef + (size_t)e0 * D_EDGE);
            const f32x2* ep1 = (const f32x2*)(ef + (size_t)e1 * D_EDGE);
            const f32x2* ep2 = (const f32x2*)(ef + (size_t)e2 * D_EDGE);
            const f32x2* ep3 = (const f32x2*)(ef + (size_t)e3 * D_EDGE);
            const float h0 = node[(size_t)s0 * D_NODE + lane];
            const float h1 = node[(size_t)s1 * D_NODE + lane];
            const float h2 = node[(size_t)s2 * D_NODE + lane];
            const float h3 = node[(size_t)s3 * D_NODE + lane];

            f32x2 a0 = {0.0f, 0.0f}, a1 = {0.0f, 0.0f};
            f32x2 a2 = {0.0f, 0.0f}, a3 = {0.0f, 0.0f};
#pragma unroll
            for (int k = 0; k < D_EDGE / 2; ++k) {
                a0 = ep0[k] * w2[k] + a0;   // -> v_pk_fma_f32
                a1 = ep1[k] * w2[k] + a1;
                a2 = ep2[k] * w2[k] + a2;
                a3 = ep3[k] * w2[k] + a3;
            }
            const float v0 = bias_e + a0.x + a0.y;
            const float v1 = bias_e + a1.x + a1.y;
            const float v2 = bias_e + a2.x + a2.y;
            const float v3 = bias_e + a3.x + a3.y;

            const float m0 = fmaxf(h0 + v0, 0.0f) + EPSF;
            const float m1 = fmaxf(h1 + v1, 0.0f) + EPSF;
            const float m2 = fmaxf(h2 + v2, 0.0f) + EPSF;
            const float m3 = fmaxf(h3 + v3, 0.0f) + EPSF;
            const float z0 = __expf(m0);
            const float z1 = __expf(m1) * k1;   // masked-off dups contribute 0
            const float z2 = __expf(m2) * k2;
            const float z3 = __expf(m3) * k3;
            num = fmaf(m0, z0, num);
            num = fmaf(m1, z1, num);
            num = fmaf(m2, z2, num);
            num = fmaf(m3, z3, num);
            den += z0 + z1 + z2 + z3;
        }

        float f = fres;
        if (c > 0)
            f += num / den;

        // Broadcast f across the wave via LDS (wave-private slot, no barrier).
        fbuf[wslot][lane] = f;
        float acc = bias_m;
#pragma unroll
        for (int d4 = 0; d4 < D_NODE / 4; ++d4) {
            const float4 fv = *(const float4*)&fbuf[wslot][d4 * 4]; // uniform -> broadcast
            acc = fmaf(fv.x, wm_s[(d4 * 4 + 0) * D_OUT + lane], acc);
            acc = fmaf(fv.y, wm_s[(d4 * 4 + 1) * D_OUT + lane], acc);
            acc = fmaf(fv.z, wm_s[(d4 * 4 + 2) * D_OUT + lane], acc);
            acc = fmaf(fv.w, wm_s[(d4 * 4 + 3) * D_OUT + lane], acc);
        }
        out[base + lane] = acc;
    }
}

extern "C" void kernel_launch(void* const* d_in, const int* in_sizes, int n_in,
                              void* d_out, int out_size, void* d_ws, size_t ws_size,
                              hipStream_t stream)
{
    const float* node = (const float*)d_in[0];
    const float* ef   = (const float*)d_in[1];
    const int*   src  = (const int*)d_in[2];
    const int*   dst  = (const int*)d_in[3];
    const float* We   = (const float*)d_in[4];
    const float* be   = (const float*)d_in[5];
    const float* Wm   = (const float*)d_in[6];
    const float* bm   = (const float*)d_in[7];
    float* out = (float*)d_out;

    const int N = in_sizes[0] / D_NODE;   // 100000
    const int E = in_sizes[2];            // 1000000

    int*  cnt   = (int*)d_ws;                 // [N]
    int2* slots = (int2*)(cnt + N);           // [N*CAP] = 51.2 MB, guarded by cnt

    hipMemsetAsync(cnt, 0, (size_t)N * sizeof(int), stream);

    genconv_build_kernel<<<(E + 255) / 256, 256, 0, stream>>>(src, dst, cnt, slots, E);

    genconv_gather_kernel<<<2048, 256, 0, stream>>>(node, ef, cnt, slots,
                                                    We, be, Wm, bm, out, N);
}

// Round 7
// 493.485 us; speedup vs baseline: 1.0076x; 1.0076x over previous
//
#include <hip/hip_runtime.h>
#include <hip/hip_bf16.h>

#define D_NODE 64
#define D_EDGE 32
#define D_OUT  64
#define EPSF   1e-7f
#define CAP    64   // max edges/node kept (deg ~ Poisson(10): P(>64) ~ 1e-32)

// ---------------------------------------------------------------------------
// Pass 1: bucket edges by destination, storing payload {edge_id, src[edge]}.
// ---------------------------------------------------------------------------
__global__ __launch_bounds__(256) void genconv_build_kernel(
    const int* __restrict__ src,
    const int* __restrict__ dst,
    int* __restrict__ cnt,            // [N] zero-init
    int2* __restrict__ slots,         // [N*CAP]
    int E)
{
    const int e = blockIdx.x * blockDim.x + threadIdx.x;
    if (e >= E) return;
    const int d = dst[e];
    const int pos = atomicAdd(&cnt[d], 1);
    if (pos < CAP)
        slots[(size_t)d * CAP + pos] = make_int2(e, src[e]);
}

// ---------------------------------------------------------------------------
// Pass 2: one wave per node, lane = output channel. Exact R4 structure
// (uniform-address slot loads -> s_load, readfirstlane-scalarized ef rows,
// 2-edge groups, scalar v_fma inner product, LDS float4 epilogue broadcast)
// + ONE change: the next slot pair is prefetched at the top of each
// iteration, so the current ef/h loads issue with zero dependent-load
// levels in front of them. Remainder via clamp-to-(c-1) + multiplicative
// mask (valid slot data, contribution zeroed).
// ---------------------------------------------------------------------------
__global__ __launch_bounds__(256) void genconv_gather_kernel(
    const float* __restrict__ node,   // [N, 64]
    const float* __restrict__ ef,     // [E, 32]
    const int* __restrict__ cnt,      // [N]
    const int2* __restrict__ slots,   // [N*CAP]
    const float* __restrict__ We,     // [32, 64]
    const float* __restrict__ be,     // [64]
    const float* __restrict__ Wm,     // [64, 64]
    const float* __restrict__ bm,     // [64]
    float* __restrict__ out,          // [N, 64]
    int N)
{
    __shared__ float wm_s[D_NODE * D_OUT];          // 16 KiB
    __shared__ __align__(16) float fbuf[4][D_NODE]; // per-wave broadcast buffer
    for (int i = threadIdx.x; i < D_NODE * D_OUT; i += blockDim.x)
        wm_s[i] = Wm[i];
    __syncthreads();

    const int lane  = threadIdx.x & 63;
    const int wslot = threadIdx.x >> 6;

    // Per-lane column of We + biases live in VGPRs for the whole kernel.
    float w[D_EDGE];
#pragma unroll
    for (int k = 0; k < D_EDGE; ++k)
        w[k] = We[k * D_OUT + lane];
    const float bias_e = be[lane];
    const float bias_m = bm[lane];

    const int wid = (int)((blockIdx.x * blockDim.x + threadIdx.x) >> 6);
    const int nw  = (int)((gridDim.x * blockDim.x) >> 6);

    for (int n = wid; n < N; n += nw) {
        const size_t base = (size_t)n * D_NODE;
        const int c = min(cnt[n], CAP);
        const int2* sl = slots + (size_t)n * CAP;

        const float fres = node[base + lane];   // residual (independent)
        float f = fres;

        if (c > 0) {
            const int last = c - 1;
            // Pipeline stage 0: first slot pair.
            int2 p0 = sl[0];
            int2 p1 = sl[min(1, last)];

            float num = 0.0f, den = 0.0f;

            for (int j = 0; j < c; j += 2) {
                const int e0 = __builtin_amdgcn_readfirstlane(p0.x);
                const int s0 = __builtin_amdgcn_readfirstlane(p0.y);
                const int e1 = __builtin_amdgcn_readfirstlane(p1.x);
                const int s1 = __builtin_amdgcn_readfirstlane(p1.y);
                const float km = (j + 1 < c) ? 1.0f : 0.0f;

                // Prefetch next pair (clamped -> always valid slot data;
                // duplicates are masked by km next iteration).
                p0 = sl[min(j + 2, last)];
                p1 = sl[min(j + 3, last)];

                const float* ep0 = ef + (size_t)e0 * D_EDGE;  // uniform -> s_load
                const float* ep1 = ef + (size_t)e1 * D_EDGE;
                const float h0 = node[(size_t)s0 * D_NODE + lane];
                const float h1 = node[(size_t)s1 * D_NODE + lane];

                float v0 = bias_e, v1 = bias_e;
#pragma unroll
                for (int k = 0; k < D_EDGE; ++k) {
                    v0 = fmaf(ep0[k], w[k], v0);   // sgpr * vgpr + vgpr
                    v1 = fmaf(ep1[k], w[k], v1);
                }
                const float m0 = fmaxf(h0 + v0, 0.0f) + EPSF;
                const float m1 = fmaxf(h1 + v1, 0.0f) + EPSF;
                const float z0 = __expf(m0);
                const float z1 = __expf(m1) * km;
                num = fmaf(m0, z0, num);
                num = fmaf(m1, z1, num);
                den += z0;
                den += z1;
            }
            f += num / den;
        }

        // Broadcast f across the wave via LDS (wave-private slot, no barrier).
        fbuf[wslot][lane] = f;
        float acc = bias_m;
#pragma unroll
        for (int d4 = 0; d4 < D_NODE / 4; ++d4) {
            const float4 fv = *(const float4*)&fbuf[wslot][d4 * 4]; // uniform -> broadcast
            acc = fmaf(fv.x, wm_s[(d4 * 4 + 0) * D_OUT + lane], acc);
            acc = fmaf(fv.y, wm_s[(d4 * 4 + 1) * D_OUT + lane], acc);
            acc = fmaf(fv.z, wm_s[(d4 * 4 + 2) * D_OUT + lane], acc);
            acc = fmaf(fv.w, wm_s[(d4 * 4 + 3) * D_OUT + lane], acc);
        }
        out[base + lane] = acc;
    }
}

extern "C" void kernel_launch(void* const* d_in, const int* in_sizes, int n_in,
                              void* d_out, int out_size, void* d_ws, size_t ws_size,
                              hipStream_t stream)
{
    const float* node = (const float*)d_in[0];
    const float* ef   = (const float*)d_in[1];
    const int*   src  = (const int*)d_in[2];
    const int*   dst  = (const int*)d_in[3];
    const float* We   = (const float*)d_in[4];
    const float* be   = (const float*)d_in[5];
    const float* Wm   = (const float*)d_in[6];
    const float* bm   = (const float*)d_in[7];
    float* out = (float*)d_out;

    const int N = in_sizes[0] / D_NODE;   // 100000
    const int E = in_sizes[2];            // 1000000

    int*  cnt   = (int*)d_ws;                 // [N]
    int2* slots = (int2*)(cnt + N);           // [N*CAP] = 51.2 MB, guarded by cnt

    hipMemsetAsync(cnt, 0, (size_t)N * sizeof(int), stream);

    genconv_build_kernel<<<(E + 255) / 256, 256, 0, stream>>>(src, dst, cnt, slots, E);

    genconv_gather_kernel<<<2048, 256, 0, stream>>>(node, ef, cnt, slots,
                                                    We, be, Wm, bm, out, N);
}